// Round 6
// baseline (201.868 us; speedup 1.0000x reference)
//
#include <hip/hip_runtime.h>

// MLPLowRankPredictor: FastFood (B,H,P,G,H,S) low-rank weight perturbation + 3-layer MLP.
// N=2048 tokens. Z=128, X=32, H=128, Y=16.
// FF blocks: wd0: 0..31 (4 rows x 32 cols), bd0: 32, wd1: 33..160 (1 row each),
//            bd1: 161, wd2: 162..177 (1 row each), bd2: 178 (first 16 elems).
// R6: two lanes/token (R5 math, verified) with the two per-wave serializers removed:
//  (a) cross-lane FWHT stage via DPP quad_perm [1,0,3,2] (pure VALU) instead of
//      __shfl_xor -> ds_bpermute (R5: 256 LDS round-trips/wave, lgkmcnt serialized);
//  (b) NO __syncthreads: 256-thread WGs, each wave owns a private 8KB LDS slice,
//      so no vmcnt(0) barrier drains -- compiler free to overlap global-load phases.
// LDS 32KB/WG -> 5 WG/CU -> 20 waves/CU ceiling (R5 measured ~9).

#define ZD 128
#define XD 32
#define HD 128
#define YD 16

typedef __fp16 f16x2 __attribute__((ext_vector_type(2)));

// lane^1 swap via DPP quad_perm [1,0,3,2] = 0xB1 (VALU, no LDS pipe).
__device__ __forceinline__ float dpp_xor1(float x) {
  return __int_as_float(__builtin_amdgcn_mov_dpp(__float_as_int(x), 0xB1, 0xF, 0xF, true));
}

// 6 within-half stages (span 1..32) then cross-lane stage (span 64) via DPP.
__device__ __forceinline__ void fwht_split(float u[64], float sgn) {
#pragma unroll
  for (int s = 1; s < 64; s <<= 1) {
#pragma unroll
    for (int p = 0; p < 64; p++) {
      if ((p & s) == 0) {
        float a = u[p], b = u[p + s];
        u[p] = a + b;
        u[p + s] = a - b;
      }
    }
  }
#pragma unroll
  for (int k = 0; k < 64; k++) {
    float t = dpp_xor1(u[k]);           // partner half's value
    u[k] = fmaf(sgn, u[k], t);          // h=0: u+t ; h=1: t-u
  }
}

// u = lane's half of z on entry; on exit u = lane's half of
// ffS * FWHT( ffG * perm( FWHT( ffB * z ) ) )   (final /128 by consumer).
// lds = THIS WAVE's private 8KB slice (64 rows x 32 tok of f16x2-packed pairs);
// same-wave DS ordering + compiler lgkmcnt waits handle the write->read dep.
__device__ __forceinline__ void ff_block2(float u[64], f16x2* lds, int tok, int h,
    float sgn, const float* __restrict__ ffB, const float* __restrict__ ffG,
    const float* __restrict__ ffS, const int* __restrict__ ffP, int j) {
  const float4* B4 = (const float4*)(ffB + j * ZD + h * 64);
  const float4* G4 = (const float4*)(ffG + j * ZD + h * 64);
  const float4* S4 = (const float4*)(ffS + j * ZD + h * 64);
  const int4*   P4 = (const int4*)(ffP + j * ZD + h * 64);
#pragma unroll
  for (int c = 0; c < 16; c++) {
    float4 f = B4[c];
    u[4 * c + 0] *= f.x; u[4 * c + 1] *= f.y; u[4 * c + 2] *= f.z; u[4 * c + 3] *= f.w;
  }
  fwht_split(u, sgn);
#pragma unroll
  for (int k = 0; k < 64; k += 2)        // row = h*32 + k/2 ; [row][tok]
    lds[(h * 32 + (k >> 1)) * 32 + tok] = __builtin_amdgcn_cvt_pkrtz(u[k], u[k + 1]);
  const __fp16* hl = (const __fp16*)lds;
#pragma unroll
  for (int c = 0; c < 16; c++) {
    int4 p = P4[c];
    float4 g = G4[c];
    u[4 * c + 0] = g.x * (float)hl[(p.x >> 1) * 64 + tok * 2 + (p.x & 1)];
    u[4 * c + 1] = g.y * (float)hl[(p.y >> 1) * 64 + tok * 2 + (p.y & 1)];
    u[4 * c + 2] = g.z * (float)hl[(p.z >> 1) * 64 + tok * 2 + (p.z & 1)];
    u[4 * c + 3] = g.w * (float)hl[(p.w >> 1) * 64 + tok * 2 + (p.w & 1)];
  }
  fwht_split(u, sgn);
#pragma unroll
  for (int c = 0; c < 16; c++) {
    float4 f = S4[c];
    u[4 * c + 0] *= f.x; u[4 * c + 1] *= f.y; u[4 * c + 2] *= f.z; u[4 * c + 3] *= f.w;
  }
}

__device__ __forceinline__ void load_half(float u[64], const float* __restrict__ src) {
  const float4* s4 = (const float4*)src;
#pragma unroll
  for (int c = 0; c < 16; c++) {
    float4 f = s4[c];
    u[4 * c + 0] = f.x; u[4 * c + 1] = f.y; u[4 * c + 2] = f.z; u[4 * c + 3] = f.w;
  }
}

// K1: grid (16, 33) x 256. wave w -> tokens (bx*4+w)*32..+31. b<32: lane h computes
// rows 4b+2h,4b+2h+1 of h1_part. b==32: h1_bias = bd0/128.
__global__ __launch_bounds__(256) void k1_layer0(
    const float* __restrict__ x, const float* __restrict__ z,
    const float* __restrict__ W0, const float* __restrict__ b0,
    const float* __restrict__ ffB, const float* __restrict__ ffG,
    const float* __restrict__ ffS, const int* __restrict__ ffP,
    float* __restrict__ h1_part, float* __restrict__ h1_bias) {
  __shared__ f16x2 lds_all[4 * 64 * 32];          // 32 KB, 8KB per wave
  const int lane = threadIdx.x & 63, wv = threadIdx.x >> 6;
  f16x2* lds = lds_all + wv * (64 * 32);
  const int tok = lane >> 1, h = lane & 1;
  const float sgn = h ? -1.f : 1.f;
  const int b = blockIdx.y;                       // 0..32 == FF block index
  const int t = (blockIdx.x * 4 + wv) * 32 + tok;

  float u[64];
  load_half(u, z + (size_t)t * ZD + h * 64);
  ff_block2(u, lds, tok, h, sgn, ffB, ffG, ffS, ffP, b);

  if (b < 32) {
    const float4* x4 = (const float4*)(x + (size_t)t * XD);
    const int r0 = 4 * b + 2 * h;
    const float4* W0a = (const float4*)(W0 + (size_t)r0 * XD);
    const float4* W0b = (const float4*)(W0 + (size_t)(r0 + 1) * XD);
    float aw0 = 0.f, aw1 = 0.f, ab0 = 0.f, ab1 = 0.f;
#pragma unroll
    for (int c = 0; c < 8; c++) {
      float4 f = x4[c];
      aw0 += u[4 * c + 0] * f.x + u[4 * c + 1] * f.y + u[4 * c + 2] * f.z + u[4 * c + 3] * f.w;
      aw1 += u[32 + 4 * c + 0] * f.x + u[32 + 4 * c + 1] * f.y + u[32 + 4 * c + 2] * f.z + u[32 + 4 * c + 3] * f.w;
      float4 wa = W0a[c], wb = W0b[c];
      ab0 += wa.x * f.x + wa.y * f.y + wa.z * f.z + wa.w * f.w;
      ab1 += wb.x * f.x + wb.y * f.y + wb.z * f.z + wb.w * f.w;
    }
    float2 o;
    o.x = ab0 + b0[r0] + aw0 * (1.0f / 128.0f);
    o.y = ab1 + b0[r0 + 1] + aw1 * (1.0f / 128.0f);
    *(float2*)(h1_part + (size_t)t * HD + r0) = o;
  } else {
    float4* o4 = (float4*)(h1_bias + (size_t)t * HD + h * 64);
#pragma unroll
    for (int c = 0; c < 16; c++)
      o4[c] = make_float4(u[4 * c] * (1.0f / 128.0f), u[4 * c + 1] * (1.0f / 128.0f),
                          u[4 * c + 2] * (1.0f / 128.0f), u[4 * c + 3] * (1.0f / 128.0f));
  }
}

// K2: grid (16, 130) x 256. jr<128: h2_part[t][jr] (pre-relu, sans bd1).
//     jr==128: h2_bias = bd1/128. jr==129: bd2buf[t][0..15] = bd2/128.
__global__ __launch_bounds__(256) void k2_layer1(
    const float* __restrict__ z,
    const float* __restrict__ W1, const float* __restrict__ b1,
    const float* __restrict__ ffB, const float* __restrict__ ffG,
    const float* __restrict__ ffS, const int* __restrict__ ffP,
    const float* __restrict__ h1_part, const float* __restrict__ h1_bias,
    float* __restrict__ h2_part, float* __restrict__ h2_bias,
    float* __restrict__ bd2buf) {
  __shared__ f16x2 lds_all[4 * 64 * 32];          // 32 KB
  const int lane = threadIdx.x & 63, wv = threadIdx.x >> 6;
  f16x2* lds = lds_all + wv * (64 * 32);
  const int tok = lane >> 1, h = lane & 1;
  const float sgn = h ? -1.f : 1.f;
  const int jr = blockIdx.y;                      // 0..129
  const int t = (blockIdx.x * 4 + wv) * 32 + tok;
  const int j = (jr < 128) ? (33 + jr) : ((jr == 128) ? 161 : 178);

  float u[64];
  load_half(u, z + (size_t)t * ZD + h * 64);
  ff_block2(u, lds, tok, h, sgn, ffB, ffG, ffS, ffP, j);

  if (jr < 128) {
    const float4* p4 = (const float4*)(h1_part + (size_t)t * HD + h * 64);
    const float4* q4 = (const float4*)(h1_bias + (size_t)t * HD + h * 64);
    const float4* W14 = (const float4*)(W1 + (size_t)jr * HD + h * 64);
    float aw = 0.f, ab = 0.f;
#pragma unroll
    for (int c = 0; c < 16; c++) {
      float4 p = p4[c], q = q4[c], w = W14[c];
      float e0 = fmaxf(p.x + q.x, 0.f), e1 = fmaxf(p.y + q.y, 0.f);
      float e2 = fmaxf(p.z + q.z, 0.f), e3 = fmaxf(p.w + q.w, 0.f);
      aw += u[4 * c] * e0 + u[4 * c + 1] * e1 + u[4 * c + 2] * e2 + u[4 * c + 3] * e3;
      ab += w.x * e0 + w.y * e1 + w.z * e2 + w.w * e3;
    }
    aw += dpp_xor1(aw);                 // combine halves (VALU, no LDS)
    ab += dpp_xor1(ab);
    if (h == 0)
      h2_part[(size_t)t * HD + jr] = ab + b1[jr] + aw * (1.0f / 128.0f);
  } else if (jr == 128) {
    float4* o4 = (float4*)(h2_bias + (size_t)t * HD + h * 64);
#pragma unroll
    for (int c = 0; c < 16; c++)
      o4[c] = make_float4(u[4 * c] * (1.0f / 128.0f), u[4 * c + 1] * (1.0f / 128.0f),
                          u[4 * c + 2] * (1.0f / 128.0f), u[4 * c + 3] * (1.0f / 128.0f));
  } else {
    if (h == 0) {                       // bd2: elements 0..15 live in half 0
      float4* o4 = (float4*)(bd2buf + (size_t)t * YD);
#pragma unroll
      for (int c = 0; c < 4; c++)
        o4[c] = make_float4(u[4 * c] * (1.0f / 128.0f), u[4 * c + 1] * (1.0f / 128.0f),
                            u[4 * c + 2] * (1.0f / 128.0f), u[4 * c + 3] * (1.0f / 128.0f));
    }
  }
}

// K3: grid (16, 16) x 256. out[t][b] = W2 row dot relu(h2) + b2 + wd2dot/128 + bd2.
__global__ __launch_bounds__(256) void k3_layer2(
    const float* __restrict__ z,
    const float* __restrict__ W2, const float* __restrict__ b2,
    const float* __restrict__ ffB, const float* __restrict__ ffG,
    const float* __restrict__ ffS, const int* __restrict__ ffP,
    const float* __restrict__ h2_part, const float* __restrict__ h2_bias,
    const float* __restrict__ bd2buf, float* __restrict__ out) {
  __shared__ f16x2 lds_all[4 * 64 * 32];          // 32 KB
  const int lane = threadIdx.x & 63, wv = threadIdx.x >> 6;
  f16x2* lds = lds_all + wv * (64 * 32);
  const int tok = lane >> 1, h = lane & 1;
  const float sgn = h ? -1.f : 1.f;
  const int b = blockIdx.y;                       // 0..15
  const int t = (blockIdx.x * 4 + wv) * 32 + tok;

  float u[64];
  load_half(u, z + (size_t)t * ZD + h * 64);
  ff_block2(u, lds, tok, h, sgn, ffB, ffG, ffS, ffP, 162 + b);

  const float4* p4 = (const float4*)(h2_part + (size_t)t * HD + h * 64);
  const float4* q4 = (const float4*)(h2_bias + (size_t)t * HD + h * 64);
  const float4* W24 = (const float4*)(W2 + (size_t)b * HD + h * 64);
  float aw = 0.f, ab = 0.f;
#pragma unroll
  for (int c = 0; c < 16; c++) {
    float4 p = p4[c], q = q4[c], w = W24[c];
    float e0 = fmaxf(p.x + q.x, 0.f), e1 = fmaxf(p.y + q.y, 0.f);
    float e2 = fmaxf(p.z + q.z, 0.f), e3 = fmaxf(p.w + q.w, 0.f);
    aw += u[4 * c] * e0 + u[4 * c + 1] * e1 + u[4 * c + 2] * e2 + u[4 * c + 3] * e3;
    ab += w.x * e0 + w.y * e1 + w.z * e2 + w.w * e3;
  }
  aw += dpp_xor1(aw);
  ab += dpp_xor1(ab);
  if (h == 0)
    out[(size_t)t * YD + b] = ab + b2[b] + aw * (1.0f / 128.0f) + bd2buf[(size_t)t * YD + b];
}

extern "C" void kernel_launch(void* const* d_in, const int* in_sizes, int n_in,
                              void* d_out, int out_size, void* d_ws, size_t ws_size,
                              hipStream_t stream) {
  const float* x  = (const float*)d_in[0];
  const float* z  = (const float*)d_in[1];
  const float* W0 = (const float*)d_in[2];
  const float* b0 = (const float*)d_in[3];
  const float* W1 = (const float*)d_in[4];
  const float* b1 = (const float*)d_in[5];
  const float* W2 = (const float*)d_in[6];
  const float* b2 = (const float*)d_in[7];
  const float* fB = (const float*)d_in[8];
  const float* fG = (const float*)d_in[9];
  const float* fS = (const float*)d_in[10];
  const int*   fP = (const int*)d_in[11];
  float* out = (float*)d_out;

  float* h1_part = (float*)d_ws;             // 2048*128 f32 = 1 MB
  float* h1_bias = h1_part + 2048 * 128;     // 1 MB
  float* h2_part = h1_bias + 2048 * 128;     // 1 MB
  float* h2_bias = h2_part + 2048 * 128;     // 1 MB
  float* bd2buf  = h2_bias + 2048 * 128;     // 2048*16 f32 = 128 KB

  k1_layer0<<<dim3(16, 33), 256, 0, stream>>>(x, z, W0, b0, fB, fG, fS, fP,
                                              h1_part, h1_bias);
  k2_layer1<<<dim3(16, 130), 256, 0, stream>>>(z, W1, b1, fB, fG, fS, fP,
                                               h1_part, h1_bias, h2_part, h2_bias, bd2buf);
  k3_layer2<<<dim3(16, 16), 256, 0, stream>>>(z, W2, b2, fB, fG, fS, fP,
                                              h2_part, h2_bias, bd2buf, out);
}